// Round 1
// baseline (5147.292 us; speedup 1.0000x reference)
//
#include <hip/hip_runtime.h>
#include <cstddef>
#include <cstdint>

#define H100  100
#define G4    400
#define BATCH 16
#define TTOT  4096
#define NIN   40

__device__ __forceinline__ float fast_rcp(float x) { return __builtin_amdgcn_rcpf(x); }

// sigmoid for i,f,o gates; tanh for g gate. Branchless: one exp + one rcp.
__device__ __forceinline__ float gate_act(float z, bool is_g) {
    float m = is_g ? -2.0f : -1.0f;
    float e = __expf(m * z);
    float r = fast_rcp(1.0f + e);
    return is_g ? (2.0f * r - 1.0f) : r;
}
__device__ __forceinline__ float tanh_fast(float x) {
    float e = __expf(-2.0f * x);
    float r = fast_rcp(1.0f + e);
    return 2.0f * r - 1.0f;
}

// ---------------------------------------------------------------------------
// Kernel 1: xg[b][t][g] = sum_i x[b][t][i] * W_ih[g][i] + b_ih[g] + b_hh[g]
// Block handles one b and up to 16 timesteps. W_ih staged transposed in LDS
// ([i][g]) so the inner dot reads are conflict-free (lanes vary g).
// ---------------------------------------------------------------------------
__global__ __launch_bounds__(256) void xg_kernel(
    const float* __restrict__ x, const float* __restrict__ W_ih,
    const float* __restrict__ b_ih, const float* __restrict__ b_hh,
    float* __restrict__ xg, int t0, int steps, int chunkT)
{
    __shared__ float W_lds[NIN * G4];     // transposed [i][g], 64 KB
    __shared__ float x_lds[16 * NIN];
    __shared__ float bias_lds[G4];

    int tid = threadIdx.x;
    int blocks_per_b = (steps + 15) >> 4;
    int b   = blockIdx.x / blocks_per_b;
    int tt  = blockIdx.x % blocks_per_b;
    int lt0 = tt * 16;
    int ntau = min(16, steps - lt0);

    for (int p = tid; p < NIN * G4; p += 256) {
        int g = p / NIN, i = p % NIN;
        W_lds[i * G4 + g] = W_ih[p];
    }
    for (int p = tid; p < G4; p += 256) bias_lds[p] = b_ih[p] + b_hh[p];
    const float* xsrc = x + ((size_t)b * TTOT + (size_t)(t0 + lt0)) * NIN;
    for (int p = tid; p < ntau * NIN; p += 256) x_lds[p] = xsrc[p];
    __syncthreads();

    int ntask = ntau * G4;
    for (int p = tid; p < ntask; p += 256) {
        int tau = p / G4, g = p % G4;
        float acc = bias_lds[g];
        #pragma unroll
        for (int i = 0; i < NIN; i++)
            acc = fmaf(x_lds[tau * NIN + i], W_lds[i * G4 + g], acc);
        xg[((size_t)b * chunkT + (size_t)(lt0 + tau)) * G4 + g] = acc;
    }
}

// ---------------------------------------------------------------------------
// Kernel 2: the sequential LSTM scan. 16 blocks (one per batch chain),
// 256 threads (4 waves = 1/SIMD). Thread x owns output rows x and 256+x
// (rows >= 400 are zero-weight dummies so all waves issue uniformly).
// W_hh rows live in registers (200 VGPRs); h broadcast via LDS float4 reads.
// ---------------------------------------------------------------------------
__global__ __launch_bounds__(256, 1) void lstm_kernel(
    const float* __restrict__ xg, const float* __restrict__ W_hh,
    float* __restrict__ hc, int t0, int steps, int chunkT)
{
    __shared__ __align__(16) float h_lds[104];
    __shared__ float a_lds[G4];

    int x = threadIdx.x;
    int b = blockIdx.x;
    bool has2 = (x < G4 - 256);            // x < 144 -> second row valid
    int  j1   = 256 + x;

    float w0[H100], w1[H100];
    #pragma unroll
    for (int k = 0; k < H100; k++) w0[k] = W_hh[x * H100 + k];
    #pragma unroll
    for (int k = 0; k < H100; k++) w1[k] = has2 ? W_hh[j1 * H100 + k] : 0.0f;

    float* hch = hc;                        // h state [16][100]
    float* hcc = hc + BATCH * H100;         // c state [16][100]

    float c = 0.0f;
    if (x < H100) {
        if (t0 == 0) {
            h_lds[x] = 0.0f;
        } else {
            h_lds[x] = hch[b * H100 + x];
            c        = hcc[b * H100 + x];
        }
    }
    const float* xgb = xg + (size_t)b * chunkT * G4;
    float xc0 = xgb[x];
    float xc1 = has2 ? xgb[j1] : 0.0f;
    __syncthreads();

    bool is_g0 = (x  >= 200) && (x  < 300);
    bool is_g1 = (j1 >= 200) && (j1 < 300);   // == (x < 44)

    for (int t = 0; t < steps; t++) {
        // prefetch next step's xg while this step computes
        float nx0 = 0.0f, nx1 = 0.0f;
        if (t + 1 < steps) {
            const float* p = xgb + (size_t)(t + 1) * G4;
            nx0 = p[x];
            if (has2) nx1 = p[j1];
        }

        float a0 = 0, a1 = 0, a2 = 0, a3 = 0;
        float c0 = 0, c1 = 0, c2 = 0, c3 = 0;
        const float4* h4 = reinterpret_cast<const float4*>(h_lds);
        #pragma unroll
        for (int k = 0; k < 25; k++) {
            float4 hv = h4[k];
            a0 = fmaf(hv.x, w0[4 * k + 0], a0);
            a1 = fmaf(hv.y, w0[4 * k + 1], a1);
            a2 = fmaf(hv.z, w0[4 * k + 2], a2);
            a3 = fmaf(hv.w, w0[4 * k + 3], a3);
            c0 = fmaf(hv.x, w1[4 * k + 0], c0);
            c1 = fmaf(hv.y, w1[4 * k + 1], c1);
            c2 = fmaf(hv.z, w1[4 * k + 2], c2);
            c3 = fmaf(hv.w, w1[4 * k + 3], c3);
        }
        float z0 = xc0 + ((a0 + a1) + (a2 + a3));
        float z1 = xc1 + ((c0 + c1) + (c2 + c3));

        a_lds[x] = gate_act(z0, is_g0);
        if (has2) a_lds[j1] = gate_act(z1, is_g1);
        __syncthreads();

        if (x < H100) {
            float gi = a_lds[x];
            float gf = a_lds[x + 100];
            float gg = a_lds[x + 200];
            float go = a_lds[x + 300];
            c = fmaf(gf, c, gi * gg);
            h_lds[x] = go * tanh_fast(c);
        }
        __syncthreads();
        xc0 = nx0; xc1 = nx1;
    }

    if (x < H100) {
        hch[b * H100 + x] = h_lds[x];
        hcc[b * H100 + x] = c;
    }
}

// ---------------------------------------------------------------------------
// Kernel 3: head. y1 = h @ W1^T + b1; BatchNorm (training mode, biased var,
// batch of 16); out = y1n @ W2^T + b2. One block.
// ---------------------------------------------------------------------------
__global__ __launch_bounds__(256) void head_kernel(
    const float* __restrict__ hc, const float* __restrict__ W1,
    const float* __restrict__ b1, const float* __restrict__ gamma,
    const float* __restrict__ beta, const float* __restrict__ W2,
    const float* __restrict__ b2, float* __restrict__ out)
{
    __shared__ float h_s[BATCH * H100];
    __shared__ float W1_s[H100 * 101];     // padded rows: conflict-free
    __shared__ float y1_s[BATCH * H100];
    __shared__ float W2_s[40 * 101];
    __shared__ float scale_s[H100], shift_s[H100];

    int tid = threadIdx.x;
    for (int p = tid; p < BATCH * H100; p += 256) h_s[p] = hc[p];
    for (int p = tid; p < H100 * H100; p += 256)
        W1_s[(p / H100) * 101 + p % H100] = W1[p];
    for (int p = tid; p < 40 * H100; p += 256)
        W2_s[(p / H100) * 101 + p % H100] = W2[p];
    __syncthreads();

    for (int p = tid; p < BATCH * H100; p += 256) {
        int b = p / H100, j = p % H100;
        float acc = b1[j];
        for (int k = 0; k < H100; k++)
            acc = fmaf(h_s[b * H100 + k], W1_s[j * 101 + k], acc);
        y1_s[b * H100 + j] = acc;
    }
    __syncthreads();

    if (tid < H100) {
        float mu = 0.0f;
        for (int b = 0; b < BATCH; b++) mu += y1_s[b * H100 + tid];
        mu *= (1.0f / BATCH);
        float var = 0.0f;
        for (int b = 0; b < BATCH; b++) {
            float d = y1_s[b * H100 + tid] - mu;
            var = fmaf(d, d, var);
        }
        var *= (1.0f / BATCH);
        float sc = gamma[tid] * rsqrtf(var + 1e-5f);
        scale_s[tid] = sc;
        shift_s[tid] = beta[tid] - mu * sc;
    }
    __syncthreads();

    for (int p = tid; p < BATCH * 40; p += 256) {
        int b = p / 40, o = p % 40;
        float acc = b2[o];
        for (int k = 0; k < H100; k++)
            acc = fmaf(fmaf(y1_s[b * H100 + k], scale_s[k], shift_s[k]),
                       W2_s[o * 101 + k], acc);
        out[p] = acc;
    }
}

// ---------------------------------------------------------------------------
extern "C" void kernel_launch(void* const* d_in, const int* in_sizes, int n_in,
                              void* d_out, int out_size, void* d_ws, size_t ws_size,
                              hipStream_t stream)
{
    const float* x     = (const float*)d_in[0];
    const float* W_ih  = (const float*)d_in[1];
    const float* W_hh  = (const float*)d_in[2];
    const float* b_ih  = (const float*)d_in[3];
    const float* b_hh  = (const float*)d_in[4];
    const float* W1    = (const float*)d_in[5];
    const float* b1    = (const float*)d_in[6];
    const float* gamma = (const float*)d_in[7];
    const float* beta  = (const float*)d_in[8];
    const float* W2    = (const float*)d_in[9];
    const float* b2    = (const float*)d_in[10];
    float* out = (float*)d_out;

    // ws layout: [0,16384) h/c state, [16384, ...) xg ring buffer
    float* hc = (float*)d_ws;
    float* xg = (float*)((char*)d_ws + 16384);
    size_t avail    = ws_size > 16384 ? ws_size - 16384 : 0;
    size_t per_step = (size_t)BATCH * G4 * sizeof(float);  // 25600 B
    size_t ct       = (avail / per_step) & ~(size_t)15;
    int chunkT = ct > TTOT ? TTOT : (int)ct;
    if (chunkT < 16) chunkT = 16;   // minimal ring; requires ws >= ~426 KB

    for (int t0 = 0; t0 < TTOT; t0 += chunkT) {
        int steps = (TTOT - t0 < chunkT) ? (TTOT - t0) : chunkT;
        int bpb = (steps + 15) / 16;
        xg_kernel<<<dim3(BATCH * bpb), 256, 0, stream>>>(
            x, W_ih, b_ih, b_hh, xg, t0, steps, chunkT);
        lstm_kernel<<<dim3(BATCH), 256, 0, stream>>>(
            xg, W_hh, hc, t0, steps, chunkT);
    }
    head_kernel<<<1, 256, 0, stream>>>(hc, W1, b1, gamma, beta, W2, b2, out);
}

// Round 5
// 4680.733 us; speedup vs baseline: 1.0997x; 1.0997x over previous
//
#include <hip/hip_runtime.h>
#include <cstddef>
#include <cstdint>

#define H100  100
#define G4    400
#define BATCH 16
#define TTOT  4096
#define NIN   40

__device__ __forceinline__ float fast_rcp(float x) { return __builtin_amdgcn_rcpf(x); }

// sigmoid for i,f,o gates; tanh for g gate. Branchless: one exp + one rcp.
__device__ __forceinline__ float gate_act(float z, bool is_g) {
    float m = is_g ? -2.0f : -1.0f;
    float e = __expf(m * z);
    float r = fast_rcp(1.0f + e);
    return is_g ? (2.0f * r - 1.0f) : r;
}
__device__ __forceinline__ float tanh_fast(float x) {
    float e = __expf(-2.0f * x);
    float r = fast_rcp(1.0f + e);
    return 2.0f * r - 1.0f;
}

// ---------------------------------------------------------------------------
// Kernel 1: xg[b][t][g] = sum_i x[b][t][i] * W_ih[g][i] + b_ih[g] + b_hh[g]
// ---------------------------------------------------------------------------
__global__ __launch_bounds__(256) void xg_kernel(
    const float* __restrict__ x, const float* __restrict__ W_ih,
    const float* __restrict__ b_ih, const float* __restrict__ b_hh,
    float* __restrict__ xg, int t0, int steps, int chunkT)
{
    __shared__ float W_lds[NIN * G4];     // transposed [i][g], 64 KB
    __shared__ float x_lds[16 * NIN];
    __shared__ float bias_lds[G4];

    int tid = threadIdx.x;
    int blocks_per_b = (steps + 15) >> 4;
    int b   = blockIdx.x / blocks_per_b;
    int tt  = blockIdx.x % blocks_per_b;
    int lt0 = tt * 16;
    int ntau = min(16, steps - lt0);

    for (int p = tid; p < NIN * G4; p += 256) {
        int g = p / NIN, i = p % NIN;
        W_lds[i * G4 + g] = W_ih[p];
    }
    for (int p = tid; p < G4; p += 256) bias_lds[p] = b_ih[p] + b_hh[p];
    const float* xsrc = x + ((size_t)b * TTOT + (size_t)(t0 + lt0)) * NIN;
    for (int p = tid; p < ntau * NIN; p += 256) x_lds[p] = xsrc[p];
    __syncthreads();

    int ntask = ntau * G4;
    for (int p = tid; p < ntask; p += 256) {
        int tau = p / G4, g = p % G4;
        float acc = bias_lds[g];
        #pragma unroll
        for (int i = 0; i < NIN; i++)
            acc = fmaf(x_lds[tau * NIN + i], W_lds[i * G4 + g], acc);
        xg[((size_t)b * chunkT + (size_t)(lt0 + tau)) * G4 + g] = acc;
    }
}

// ---------------------------------------------------------------------------
// Kernel 2: the sequential LSTM scan. 16 blocks (one per batch chain),
// 512 threads (8 waves, 2/SIMD). Thread x<400 owns ONE output row; its 100
// W_hh weights live in registers (~100 VGPRs -> no spill at the 256 cap).
// h is broadcast via same-address LDS float4 reads (conflict-free).
// ---------------------------------------------------------------------------
__global__ __launch_bounds__(512, 2) void lstm_kernel(
    const float* __restrict__ xg, const float* __restrict__ W_hh,
    float* __restrict__ hc, int t0, int steps, int chunkT)
{
    __shared__ __align__(16) float h_lds[104];
    __shared__ float a_lds[G4];

    int x = threadIdx.x;
    int b = blockIdx.x;
    bool valid = (x < G4);
    int  r     = valid ? x : 0;            // clamp for safe addressing

    float w[H100];
    const float* wrow = W_hh + (size_t)r * H100;
    #pragma unroll
    for (int k = 0; k < H100; k++) w[k] = wrow[k];

    float* hch = hc;                        // h state [16][100]
    float* hcc = hc + BATCH * H100;         // c state [16][100]

    float c = 0.0f;
    if (x < H100) {
        if (t0 == 0) {
            h_lds[x] = 0.0f;
        } else {
            h_lds[x] = hch[b * H100 + x];
            c        = hcc[b * H100 + x];
        }
    }
    const float* xgb = xg + (size_t)b * chunkT * G4;
    float xc = valid ? xgb[r] : 0.0f;
    __syncthreads();

    bool is_g = (x >= 200) && (x < 300);

    for (int t = 0; t < steps; t++) {
        // prefetch next step's xg while this step computes
        float nx = 0.0f;
        if (valid && (t + 1 < steps)) nx = xgb[(size_t)(t + 1) * G4 + r];

        float a0 = 0, a1 = 0, a2 = 0, a3 = 0;
        const float4* h4 = reinterpret_cast<const float4*>(h_lds);
        #pragma unroll
        for (int k = 0; k < 25; k++) {
            float4 hv = h4[k];
            a0 = fmaf(hv.x, w[4 * k + 0], a0);
            a1 = fmaf(hv.y, w[4 * k + 1], a1);
            a2 = fmaf(hv.z, w[4 * k + 2], a2);
            a3 = fmaf(hv.w, w[4 * k + 3], a3);
        }
        float z = xc + ((a0 + a1) + (a2 + a3));

        if (valid) a_lds[x] = gate_act(z, is_g);
        __syncthreads();

        if (x < H100) {
            float gi = a_lds[x];
            float gf = a_lds[x + 100];
            float gg = a_lds[x + 200];
            float go = a_lds[x + 300];
            c = fmaf(gf, c, gi * gg);
            h_lds[x] = go * tanh_fast(c);
        }
        __syncthreads();
        xc = nx;
    }

    if (x < H100) {
        hch[b * H100 + x] = h_lds[x];
        hcc[b * H100 + x] = c;
    }
}

// ---------------------------------------------------------------------------
// Kernel 3: head. y1 = h @ W1^T + b1; BatchNorm (training mode, biased var,
// batch of 16); out = y1n @ W2^T + b2. One block.
// ---------------------------------------------------------------------------
__global__ __launch_bounds__(256) void head_kernel(
    const float* __restrict__ hc, const float* __restrict__ W1,
    const float* __restrict__ b1, const float* __restrict__ gamma,
    const float* __restrict__ beta, const float* __restrict__ W2,
    const float* __restrict__ b2, float* __restrict__ out)
{
    __shared__ float h_s[BATCH * H100];
    __shared__ float W1_s[H100 * 101];     // padded rows: conflict-free
    __shared__ float y1_s[BATCH * H100];
    __shared__ float W2_s[40 * 101];
    __shared__ float scale_s[H100], shift_s[H100];

    int tid = threadIdx.x;
    for (int p = tid; p < BATCH * H100; p += 256) h_s[p] = hc[p];
    for (int p = tid; p < H100 * H100; p += 256)
        W1_s[(p / H100) * 101 + p % H100] = W1[p];
    for (int p = tid; p < 40 * H100; p += 256)
        W2_s[(p / H100) * 101 + p % H100] = W2[p];
    __syncthreads();

    for (int p = tid; p < BATCH * H100; p += 256) {
        int b = p / H100, j = p % H100;
        float acc = b1[j];
        for (int k = 0; k < H100; k++)
            acc = fmaf(h_s[b * H100 + k], W1_s[j * 101 + k], acc);
        y1_s[b * H100 + j] = acc;
    }
    __syncthreads();

    if (tid < H100) {
        float mu = 0.0f;
        for (int b = 0; b < BATCH; b++) mu += y1_s[b * H100 + tid];
        mu *= (1.0f / BATCH);
        float var = 0.0f;
        for (int b = 0; b < BATCH; b++) {
            float d = y1_s[b * H100 + tid] - mu;
            var = fmaf(d, d, var);
        }
        var *= (1.0f / BATCH);
        float sc = gamma[tid] * rsqrtf(var + 1e-5f);
        scale_s[tid] = sc;
        shift_s[tid] = beta[tid] - mu * sc;
    }
    __syncthreads();

    for (int p = tid; p < BATCH * 40; p += 256) {
        int b = p / 40, o = p % 40;
        float acc = b2[o];
        for (int k = 0; k < H100; k++)
            acc = fmaf(fmaf(y1_s[b * H100 + k], scale_s[k], shift_s[k]),
                       W2_s[o * 101 + k], acc);
        out[p] = acc;
    }
}

// ---------------------------------------------------------------------------
extern "C" void kernel_launch(void* const* d_in, const int* in_sizes, int n_in,
                              void* d_out, int out_size, void* d_ws, size_t ws_size,
                              hipStream_t stream)
{
    const float* x     = (const float*)d_in[0];
    const float* W_ih  = (const float*)d_in[1];
    const float* W_hh  = (const float*)d_in[2];
    const float* b_ih  = (const float*)d_in[3];
    const float* b_hh  = (const float*)d_in[4];
    const float* W1    = (const float*)d_in[5];
    const float* b1    = (const float*)d_in[6];
    const float* gamma = (const float*)d_in[7];
    const float* beta  = (const float*)d_in[8];
    const float* W2    = (const float*)d_in[9];
    const float* b2    = (const float*)d_in[10];
    float* out = (float*)d_out;

    // ws layout: [0,16384) h/c state, [16384, ...) xg ring buffer
    float* hc = (float*)d_ws;
    float* xg = (float*)((char*)d_ws + 16384);
    size_t avail    = ws_size > 16384 ? ws_size - 16384 : 0;
    size_t per_step = (size_t)BATCH * G4 * sizeof(float);  // 25600 B
    size_t ct       = (avail / per_step) & ~(size_t)15;
    int chunkT = ct > TTOT ? TTOT : (int)ct;
    if (chunkT < 16) chunkT = 16;   // minimal ring; requires ws >= ~426 KB

    for (int t0 = 0; t0 < TTOT; t0 += chunkT) {
        int steps = (TTOT - t0 < chunkT) ? (TTOT - t0) : chunkT;
        int bpb = (steps + 15) / 16;
        xg_kernel<<<dim3(BATCH * bpb), 256, 0, stream>>>(
            x, W_ih, b_ih, b_hh, xg, t0, steps, chunkT);
        lstm_kernel<<<dim3(BATCH), 512, 0, stream>>>(
            xg, W_hh, hc, t0, steps, chunkT);
    }
    head_kernel<<<1, 256, 0, stream>>>(hc, W1, b1, gamma, beta, W2, b2, out);
}

// Round 6
// 3449.235 us; speedup vs baseline: 1.4923x; 1.3570x over previous
//
#include <hip/hip_runtime.h>
#include <cstddef>
#include <cstdint>

#define H100  100
#define G4    400
#define BATCH 16
#define TTOT  4096
#define NIN   40

__device__ __forceinline__ float fast_rcp(float x) { return __builtin_amdgcn_rcpf(x); }

// sigmoid for i,f,o gates; tanh for g gate. Branchless: one exp + one rcp.
__device__ __forceinline__ float gate_act(float z, bool is_g) {
    float m = is_g ? -2.0f : -1.0f;
    float e = __expf(m * z);
    float r = fast_rcp(1.0f + e);
    return is_g ? (2.0f * r - 1.0f) : r;
}
__device__ __forceinline__ float tanh_fast(float x) {
    float e = __expf(-2.0f * x);
    float r = fast_rcp(1.0f + e);
    return 2.0f * r - 1.0f;
}

// ---------------------------------------------------------------------------
// Kernel 1: xg[b][t][g] = sum_i x[b][t][i] * W_ih[g][i] + b_ih[g] + b_hh[g]
// ---------------------------------------------------------------------------
__global__ __launch_bounds__(256) void xg_kernel(
    const float* __restrict__ x, const float* __restrict__ W_ih,
    const float* __restrict__ b_ih, const float* __restrict__ b_hh,
    float* __restrict__ xg, int t0, int steps, int chunkT)
{
    __shared__ float W_lds[NIN * G4];     // transposed [i][g], 64 KB
    __shared__ float x_lds[16 * NIN];
    __shared__ float bias_lds[G4];

    int tid = threadIdx.x;
    int blocks_per_b = (steps + 15) >> 4;
    int b   = blockIdx.x / blocks_per_b;
    int tt  = blockIdx.x % blocks_per_b;
    int lt0 = tt * 16;
    int ntau = min(16, steps - lt0);

    for (int p = tid; p < NIN * G4; p += 256) {
        int g = p / NIN, i = p % NIN;
        W_lds[i * G4 + g] = W_ih[p];
    }
    for (int p = tid; p < G4; p += 256) bias_lds[p] = b_ih[p] + b_hh[p];
    const float* xsrc = x + ((size_t)b * TTOT + (size_t)(t0 + lt0)) * NIN;
    for (int p = tid; p < ntau * NIN; p += 256) x_lds[p] = xsrc[p];
    __syncthreads();

    int ntask = ntau * G4;
    for (int p = tid; p < ntask; p += 256) {
        int tau = p / G4, g = p % G4;
        float acc = bias_lds[g];
        #pragma unroll
        for (int i = 0; i < NIN; i++)
            acc = fmaf(x_lds[tau * NIN + i], W_lds[i * G4 + g], acc);
        xg[((size_t)b * chunkT + (size_t)(lt0 + tau)) * G4 + g] = acc;
    }
}

// ---------------------------------------------------------------------------
// Kernel 2: LSTM scan. 16 blocks (one per chain), 256 threads (4 waves,
// 1/SIMD). Thread x owns rows x and x+256. Weights in 50 NAMED float4
// registers (defeats SROA failure -> no spill). h lives replicated in every
// wave's registers (lane l: h[l], h[64+l]); the dot product broadcasts h[k]
// via v_readlane (VALU pipe) -- NO per-thread LDS h reads (the R5 wall:
// 200 ds_read_b128/step = 2400 cy on the per-CU LDS pipe). Gates cross
// threads through a double-buffered a_lds with ONE barrier per step; every
// wave redundantly recomputes the c/h update so h never round-trips LDS.
// ---------------------------------------------------------------------------
#define RLF(src, idx) __int_as_float(__builtin_amdgcn_readlane(__float_as_int(src), (idx)))

__global__ __launch_bounds__(256, 1) void lstm_kernel(
    const float* __restrict__ xg, const float* __restrict__ W_hh,
    float* __restrict__ hc, int t0, int steps, int chunkT)
{
    __shared__ float a_lds[2][G4];

    const int x = threadIdx.x;
    const int b = blockIdx.x;
    const int l = x & 63;
    const bool hasB = (x < G4 - 256);          // x < 144: second row valid
    const int  rA = x;
    const int  rB = hasB ? (x + 256) : 0;      // clamp for safe addressing

    const float4* wra = (const float4*)(W_hh + (size_t)rA * H100);
    const float4* wrb = (const float4*)(W_hh + (size_t)rB * H100);
#define LDW(q) const float4 wa##q = wra[q]; const float4 wb##q = wrb[q];
    LDW(0)  LDW(1)  LDW(2)  LDW(3)  LDW(4)  LDW(5)  LDW(6)  LDW(7)
    LDW(8)  LDW(9)  LDW(10) LDW(11) LDW(12) LDW(13) LDW(14) LDW(15)
    LDW(16) LDW(17) LDW(18) LDW(19) LDW(20) LDW(21) LDW(22) LDW(23)
    LDW(24)
#undef LDW

    float* hch = hc;                        // h state [16][100]
    float* hcc = hc + BATCH * H100;         // c state [16][100]

    // replicated state: lane l holds channel l (and 64+l when l<36)
    float h0 = 0.f, h1 = 0.f, c0 = 0.f, c1 = 0.f;
    if (t0 != 0) {
        h0 = hch[b * H100 + l];
        c0 = hcc[b * H100 + l];
        if (l < 36) {
            h1 = hch[b * H100 + 64 + l];
            c1 = hcc[b * H100 + 64 + l];
        }
    }

    const float* xgb = xg + (size_t)b * chunkT * G4;
    float xcA = xgb[rA];
    float xcB = hasB ? xgb[rB] : 0.0f;

    const bool is_gA = (x >= 200) && (x < 300);
    const bool is_gB = (x < 44);               // row x+256 in [200,300)

#define DOTQ(q, u0_, u1_, u2_, u3_) \
    aA0 = fmaf(u0_, wa##q.x, aA0); aB0 = fmaf(u0_, wb##q.x, aB0); \
    aA1 = fmaf(u1_, wa##q.y, aA1); aB1 = fmaf(u1_, wb##q.y, aB1); \
    aA2 = fmaf(u2_, wa##q.z, aA2); aB2 = fmaf(u2_, wb##q.z, aB2); \
    aA3 = fmaf(u3_, wa##q.w, aA3); aB3 = fmaf(u3_, wb##q.w, aB3);
#define DOT_LO(q) { const float u0 = RLF(h0, 4*q+0), u1 = RLF(h0, 4*q+1), \
                               u2 = RLF(h0, 4*q+2), u3 = RLF(h0, 4*q+3); \
                    DOTQ(q, u0, u1, u2, u3) }
#define DOT_HI(q) { const float u0 = RLF(h1, 4*q-64), u1 = RLF(h1, 4*q-63), \
                               u2 = RLF(h1, 4*q-62), u3 = RLF(h1, 4*q-61); \
                    DOTQ(q, u0, u1, u2, u3) }

    #pragma unroll 1
    for (int t = 0; t < steps; t++) {
        // prefetch next step's xg (hides HBM/L2 latency under compute)
        float nxA = 0.f, nxB = 0.f;
        if (t + 1 < steps) {
            const float* p = xgb + (size_t)(t + 1) * G4;
            nxA = p[rA];
            nxB = p[rB];
        }

        float aA0 = 0, aA1 = 0, aA2 = 0, aA3 = 0;
        float aB0 = 0, aB1 = 0, aB2 = 0, aB3 = 0;
        DOT_LO(0)  DOT_LO(1)  DOT_LO(2)  DOT_LO(3)
        DOT_LO(4)  DOT_LO(5)  DOT_LO(6)  DOT_LO(7)
        DOT_LO(8)  DOT_LO(9)  DOT_LO(10) DOT_LO(11)
        DOT_LO(12) DOT_LO(13) DOT_LO(14) DOT_LO(15)
        DOT_HI(16) DOT_HI(17) DOT_HI(18) DOT_HI(19)
        DOT_HI(20) DOT_HI(21) DOT_HI(22) DOT_HI(23)
        DOT_HI(24)

        float zA = xcA + ((aA0 + aA1) + (aA2 + aA3));
        float zB = xcB + ((aB0 + aB1) + (aB2 + aB3));

        const int par = t & 1;
        a_lds[par][rA] = gate_act(zA, is_gA);
        if (hasB) a_lds[par][x + 256] = gate_act(zB, is_gB);
        __syncthreads();

        // every wave redundantly updates the full c/h state in registers
        const float* ab = a_lds[par];
        {
            float gi = ab[l], gf = ab[100 + l], gg = ab[200 + l], go = ab[300 + l];
            c0 = fmaf(gf, c0, gi * gg);
            h0 = go * tanh_fast(c0);
        }
        if (l < 36) {
            float gi = ab[64 + l], gf = ab[164 + l], gg = ab[264 + l], go = ab[364 + l];
            c1 = fmaf(gf, c1, gi * gg);
            h1 = go * tanh_fast(c1);
        }
        xcA = nxA; xcB = nxB;
    }

    if (x < 64) {                       // wave 0 writes the carried state
        hch[b * H100 + l] = h0;
        hcc[b * H100 + l] = c0;
        if (l < 36) {
            hch[b * H100 + 64 + l] = h1;
            hcc[b * H100 + 64 + l] = c1;
        }
    }
#undef DOTQ
#undef DOT_LO
#undef DOT_HI
}

// ---------------------------------------------------------------------------
// Kernel 3: head. y1 = h @ W1^T + b1; BatchNorm (training mode, biased var,
// batch of 16); out = y1n @ W2^T + b2. One block.
// ---------------------------------------------------------------------------
__global__ __launch_bounds__(256) void head_kernel(
    const float* __restrict__ hc, const float* __restrict__ W1,
    const float* __restrict__ b1, const float* __restrict__ gamma,
    const float* __restrict__ beta, const float* __restrict__ W2,
    const float* __restrict__ b2, float* __restrict__ out)
{
    __shared__ float h_s[BATCH * H100];
    __shared__ float W1_s[H100 * 101];     // padded rows: conflict-free
    __shared__ float y1_s[BATCH * H100];
    __shared__ float W2_s[40 * 101];
    __shared__ float scale_s[H100], shift_s[H100];

    int tid = threadIdx.x;
    for (int p = tid; p < BATCH * H100; p += 256) h_s[p] = hc[p];
    for (int p = tid; p < H100 * H100; p += 256)
        W1_s[(p / H100) * 101 + p % H100] = W1[p];
    for (int p = tid; p < 40 * H100; p += 256)
        W2_s[(p / H100) * 101 + p % H100] = W2[p];
    __syncthreads();

    for (int p = tid; p < BATCH * H100; p += 256) {
        int b = p / H100, j = p % H100;
        float acc = b1[j];
        for (int k = 0; k < H100; k++)
            acc = fmaf(h_s[b * H100 + k], W1_s[j * 101 + k], acc);
        y1_s[b * H100 + j] = acc;
    }
    __syncthreads();

    if (tid < H100) {
        float mu = 0.0f;
        for (int b = 0; b < BATCH; b++) mu += y1_s[b * H100 + tid];
        mu *= (1.0f / BATCH);
        float var = 0.0f;
        for (int b = 0; b < BATCH; b++) {
            float d = y1_s[b * H100 + tid] - mu;
            var = fmaf(d, d, var);
        }
        var *= (1.0f / BATCH);
        float sc = gamma[tid] * rsqrtf(var + 1e-5f);
        scale_s[tid] = sc;
        shift_s[tid] = beta[tid] - mu * sc;
    }
    __syncthreads();

    for (int p = tid; p < BATCH * 40; p += 256) {
        int b = p / 40, o = p % 40;
        float acc = b2[o];
        for (int k = 0; k < H100; k++)
            acc = fmaf(fmaf(y1_s[b * H100 + k], scale_s[k], shift_s[k]),
                       W2_s[o * 101 + k], acc);
        out[p] = acc;
    }
}

// ---------------------------------------------------------------------------
extern "C" void kernel_launch(void* const* d_in, const int* in_sizes, int n_in,
                              void* d_out, int out_size, void* d_ws, size_t ws_size,
                              hipStream_t stream)
{
    const float* x     = (const float*)d_in[0];
    const float* W_ih  = (const float*)d_in[1];
    const float* W_hh  = (const float*)d_in[2];
    const float* b_ih  = (const float*)d_in[3];
    const float* b_hh  = (const float*)d_in[4];
    const float* W1    = (const float*)d_in[5];
    const float* b1    = (const float*)d_in[6];
    const float* gamma = (const float*)d_in[7];
    const float* beta  = (const float*)d_in[8];
    const float* W2    = (const float*)d_in[9];
    const float* b2    = (const float*)d_in[10];
    float* out = (float*)d_out;

    // ws layout: [0,16384) h/c state, [16384, ...) xg ring buffer
    float* hc = (float*)d_ws;
    float* xg = (float*)((char*)d_ws + 16384);
    size_t avail    = ws_size > 16384 ? ws_size - 16384 : 0;
    size_t per_step = (size_t)BATCH * G4 * sizeof(float);  // 25600 B
    size_t ct       = (avail / per_step) & ~(size_t)15;
    int chunkT = ct > TTOT ? TTOT : (int)ct;
    if (chunkT < 16) chunkT = 16;   // minimal ring; requires ws >= ~426 KB

    for (int t0 = 0; t0 < TTOT; t0 += chunkT) {
        int steps = (TTOT - t0 < chunkT) ? (TTOT - t0) : chunkT;
        int bpb = (steps + 15) / 16;
        xg_kernel<<<dim3(BATCH * bpb), 256, 0, stream>>>(
            x, W_ih, b_ih, b_hh, xg, t0, steps, chunkT);
        lstm_kernel<<<dim3(BATCH), 256, 0, stream>>>(
            xg, W_hh, hc, t0, steps, chunkT);
    }
    head_kernel<<<1, 256, 0, stream>>>(hc, W1, b1, gamma, beta, W2, b2, out);
}